// Round 8
// baseline (438.519 us; speedup 1.0000x reference)
//
#include <hip/hip_runtime.h>

// FlowNetC correlation: B=8, C=128, H=128, W=256, PAD=4, MD=4, K=1, S1=S2=1
// out[b, dyi*9+dxi, h, w] = (1/128) * sum_c in1[b,c,h,w] * in2[b,c,h+dyi-4,w+dxi-4]
// (in2 zero outside bounds)
//
// R5 (6th submit; infra flake streak, never measured): latency-attack
// restructure (R4 measured: dispatch 247us, VALUBusy 23%, HBM 13%, VGPR 64 ->
// latency-bound, every pipe idle).
//  - wave = one (b, h, dy) output row: 64 lanes x 4 px. 9216 waves (2x R4)
//    -> 36 waves/CU schedulable; acc[4][9] = 36 VGPR.
//  - no shuffles: 12-float in2 window = 3 aligned float4 loads (w0-4,w0,w0+4;
//    w0 = 4*lane so all 16B-aligned). Critical path is vmcnt->FMA only.
//    Overlapping B-reads across neighbor lanes are L1 hits.
//  - depth-2 register pipeline: two named E/O sets (static indexing only),
//    FMA for channel c waits on loads issued at c-2.
//  - 32-bit offsets from wave-uniform bases; edge lanes clamp, garbage feeds
//    only epilogue-killed acc entries (lane0: p+d<4, lane63: p+d>7).
// XCD swizzle: 2304 blocks = 8 XCD x 288; XCD x owns exactly b = x.

#define NB 8
#define NC 128
#define NH 128
#define NW 256
#define ND 9
#define CH 32768                 // NH*NW floats = channel stride
#define SCALE (1.0f / 128.0f)

__global__ __launch_bounds__(256, 4) void corr_kernel(
    const float* __restrict__ in1, const float* __restrict__ in2,
    float* __restrict__ out)
{
    const int bid = blockIdx.x;
    const int sid = (bid & 7) * 288 + (bid >> 3);     // XCD-contiguous
    const int id  = sid * 4 + (threadIdx.x >> 6);     // 0..9215
    const int g   = threadIdx.x & 63;

    const int dyi  = id % ND;
    const int rest = id / ND;        // 0..1023
    const int h    = rest & 127;
    const int b    = rest >> 7;

    const int w0 = g << 2;           // 4 px per lane: w0..w0+3
    const int hh = h + dyi - 4;      // in2 source row (wave-uniform)
    const bool valid = ((unsigned)hh < (unsigned)NH);
    const int hhc = valid ? hh : 0;

    const float* __restrict__ pa = in1 + (size_t)(b * NC * NH + h)   * NW;
    const float* __restrict__ pb = in2 + (size_t)(b * NC * NH + hhc) * NW;

    // 32-bit running offsets (max 127*32768+259 < 2^23)
    int oa  = w0;
    int ob0 = (g == 0)  ? 0  : (w0 - 4);   // bw[0..3]  = in2[w0-4..w0-1]
    int ob1 = w0;                          // bw[4..7]  = in2[w0..w0+3]
    int ob2 = (g == 63) ? w0 : (w0 + 4);   // bw[8..11] = in2[w0+4..w0+7]

    float acc[4][ND];
#pragma unroll
    for (int p = 0; p < 4; ++p)
#pragma unroll
        for (int d = 0; d < ND; ++d) acc[p][d] = 0.f;

    // prologue: load channel 0 (E) and channel 1 (O)
    float4 A_e = *(const float4*)(pa + oa);
    float4 P_e = *(const float4*)(pb + ob0);
    float4 Q_e = *(const float4*)(pb + ob1);
    float4 R_e = *(const float4*)(pb + ob2);
    oa += CH; ob0 += CH; ob1 += CH; ob2 += CH;
    float4 A_o = *(const float4*)(pa + oa);
    float4 P_o = *(const float4*)(pb + ob0);
    float4 Q_o = *(const float4*)(pb + ob1);
    float4 R_o = *(const float4*)(pb + ob2);
    oa += CH; ob0 += CH; ob1 += CH; ob2 += CH;

#pragma unroll 1
    for (int c = 0; c < NC - 2; c += 2) {
        {   // channel c (E): snapshot, issue c+2 into E regs, then FMA
            const float a_[4]  = {A_e.x, A_e.y, A_e.z, A_e.w};
            const float bw[12] = {P_e.x, P_e.y, P_e.z, P_e.w,
                                  Q_e.x, Q_e.y, Q_e.z, Q_e.w,
                                  R_e.x, R_e.y, R_e.z, R_e.w};
            A_e = *(const float4*)(pa + oa);
            P_e = *(const float4*)(pb + ob0);
            Q_e = *(const float4*)(pb + ob1);
            R_e = *(const float4*)(pb + ob2);
            oa += CH; ob0 += CH; ob1 += CH; ob2 += CH;
#pragma unroll
            for (int p = 0; p < 4; ++p)
#pragma unroll
                for (int d = 0; d < ND; ++d)
                    acc[p][d] += a_[p] * bw[p + d];
        }
        {   // channel c+1 (O): snapshot, issue c+3 into O regs, then FMA
            const float a_[4]  = {A_o.x, A_o.y, A_o.z, A_o.w};
            const float bw[12] = {P_o.x, P_o.y, P_o.z, P_o.w,
                                  Q_o.x, Q_o.y, Q_o.z, Q_o.w,
                                  R_o.x, R_o.y, R_o.z, R_o.w};
            A_o = *(const float4*)(pa + oa);
            P_o = *(const float4*)(pb + ob0);
            Q_o = *(const float4*)(pb + ob1);
            R_o = *(const float4*)(pb + ob2);
            oa += CH; ob0 += CH; ob1 += CH; ob2 += CH;
#pragma unroll
            for (int p = 0; p < 4; ++p)
#pragma unroll
                for (int d = 0; d < ND; ++d)
                    acc[p][d] += a_[p] * bw[p + d];
        }
    }
    {   // tail: channels 126 (E) and 127 (O), no more loads
        const float a_[4]  = {A_e.x, A_e.y, A_e.z, A_e.w};
        const float bw[12] = {P_e.x, P_e.y, P_e.z, P_e.w,
                              Q_e.x, Q_e.y, Q_e.z, Q_e.w,
                              R_e.x, R_e.y, R_e.z, R_e.w};
#pragma unroll
        for (int p = 0; p < 4; ++p)
#pragma unroll
            for (int d = 0; d < ND; ++d)
                acc[p][d] += a_[p] * bw[p + d];
    }
    {
        const float a_[4]  = {A_o.x, A_o.y, A_o.z, A_o.w};
        const float bw[12] = {P_o.x, P_o.y, P_o.z, P_o.w,
                              Q_o.x, Q_o.y, Q_o.z, Q_o.w,
                              R_o.x, R_o.y, R_o.z, R_o.w};
#pragma unroll
        for (int p = 0; p < 4; ++p)
#pragma unroll
            for (int d = 0; d < ND; ++d)
                acc[p][d] += a_[p] * bw[p + d];
    }

    // epilogue: zero entries whose in2 sample is out of bounds, scale, store
    float* outp = out + ((size_t)(b * (ND * ND) + dyi * ND) * NH + h) * NW + w0;
#pragma unroll
    for (int d = 0; d < ND; ++d) {
        float v[4];
#pragma unroll
        for (int p = 0; p < 4; ++p) {
            const bool kill = (!valid) ||
                              (g == 0  && (p + d) < 4) ||   // w-sample < 0
                              (g == 63 && (p + d) > 7);     // w-sample > 255
            v[p] = kill ? 0.0f : acc[p][d] * SCALE;
        }
        float4 o4 = {v[0], v[1], v[2], v[3]};
        *(float4*)(outp + (size_t)d * CH) = o4;
    }
}

extern "C" void kernel_launch(void* const* d_in, const int* in_sizes, int n_in,
                              void* d_out, int out_size, void* d_ws, size_t ws_size,
                              hipStream_t stream) {
    const float* in1 = (const float*)d_in[0];
    const float* in2 = (const float*)d_in[1];
    float* out = (float*)d_out;
    corr_kernel<<<dim3(2304), dim3(256), 0, stream>>>(in1, in2, out);
}